// Round 5
// baseline (190.218 us; speedup 1.0000x reference)
//
#include <hip/hip_runtime.h>

// Problem constants (fixed by setup_inputs):
//   a_arc, s_arc : [64, 1024, 1024] f32
//   adds, pos    : [64, 1024] int32 in [0, 50)
constexpr int NPOS  = 50;
constexpr int NBINS = NPOS * NPOS;   // 2500
constexpr int SL    = 1024;
constexpr int BZ    = 64;
constexpr float ALPHA = 0.3f;

// ---------------- hist kernel config ----------------
constexpr int H_THREADS = 128;                 // 2 adjacent columns per thread
constexpr int H_COLS    = 2 * H_THREADS;       // 256 columns per block
constexpr int COLCHUNKS = SL / H_COLS;         // 4
constexpr int ROWSPLITS = 2;
constexpr int H_ROWS    = SL / ROWSPLITS;      // 512 rows per block
constexpr int H_BLOCKS  = BZ * COLCHUNKS * ROWSPLITS;   // 512 (2 blocks/CU)

// ---------------- apply kernel config ----------------
constexpr int A_THREADS       = 256;
constexpr int ROWS_PER_BLOCK  = 32;
constexpr int BLOCKS_PER_B    = SL / ROWS_PER_BLOCK;    // 32
constexpr int A_BLOCKS        = BZ * BLOCKS_PER_B;      // 2048

// ---------------------------------------------------------------------------
// Kernel 1: histogram, zero atomics in the main loop (round-3 structure) PLUS:
//  - accA/accB are DISTINCT LDS allocations (thread's two adjacent columns):
//    compiler can prove non-alias -> two independent RMW chains (ILP 2),
//    instead of one serialized chain at LDS-RAW latency.
//  - explicit 2-deep software pipeline: next 16 rows' float2 loads are issued
//    BEFORE the current RMW chain, keeping ~16 loads/wave in flight.
// ---------------------------------------------------------------------------
__global__ __launch_bounds__(H_THREADS) void hist_kernel(
    const float* __restrict__ a, const int* __restrict__ adds,
    float* __restrict__ g_hist) {
  __shared__ float accA[NPOS][H_THREADS];   // 25.6 KB (even columns)
  __shared__ float accB[NPOS][H_THREADS];   // 25.6 KB (odd  columns)
  __shared__ int   adds_s[SL];              // 4 KB
  __shared__ int   cnt2[NPOS];
  __shared__ int   off2s[NPOS];
  __shared__ int   off2m[NPOS];
  __shared__ int   order2[H_COLS];

  const int tid    = threadIdx.x;
  const int b      = blockIdx.x / (COLCHUNKS * ROWSPLITS);
  const int rem    = blockIdx.x % (COLCHUNKS * ROWSPLITS);
  const int cc     = rem / ROWSPLITS;
  const int rsplit = rem % ROWSPLITS;
  const int i0     = rsplit * H_ROWS;

  // Stage adds row; zero accumulators and counters.
  {
    const int4* src = (const int4*)(adds + (size_t)b * SL);
    ((int4*)adds_s)[tid]             = src[tid];
    ((int4*)adds_s)[tid + H_THREADS] = src[tid + H_THREADS];
  }
  #pragma unroll
  for (int p = 0; p < NPOS; ++p) { accA[p][tid] = 0.0f; accB[p][tid] = 0.0f; }
  if (tid < NPOS) cnt2[tid] = 0;
  __syncthreads();

  const int j0 = cc * H_COLS + 2 * tid;     // this thread's even column
  const int q0 = adds_s[j0];                // its two fixed column-bins
  const int q1 = adds_s[j0 + 1];

  const float2* __restrict__ P =
      (const float2*)(a + ((size_t)b * SL + i0) * SL + j0);
  constexpr int RSTRIDE = SL / 2;           // row stride in float2 units

  auto loadset = [&](float2 (&v)[16], int (&bs)[16], int R0) {
    #pragma unroll
    for (int k = 0; k < 16; ++k)            // 16 independent 512B/wave loads
      v[k] = P[(size_t)(R0 + k) * RSTRIDE];
    #pragma unroll
    for (int k4 = 0; k4 < 4; ++k4) {        // wave-uniform broadcast reads
      const int4 b4 = *(const int4*)&adds_s[i0 + R0 + k4 * 4];
      bs[k4 * 4 + 0] = b4.x; bs[k4 * 4 + 1] = b4.y;
      bs[k4 * 4 + 2] = b4.z; bs[k4 * 4 + 3] = b4.w;
    }
  };
  auto rmwset = [&](float2 (&v)[16], int (&bs)[16]) {
    #pragma unroll
    for (int k = 0; k < 16; ++k) {          // two independent chains (A,B)
      accA[bs[k]][tid] += v[k].x;
      accB[bs[k]][tid] += v[k].y;
    }
  };

  float2 v0[16], v1[16];
  int    bs0[16], bs1[16];
  loadset(v0, bs0, 0);
  for (int r0 = 0; r0 < H_ROWS; r0 += 32) { // 16 iterations, ping-pong
    loadset(v1, bs1, r0 + 16);              // in flight during rmwset(v0)
    rmwset(v0, bs0);
    if (r0 + 32 < H_ROWS) loadset(v0, bs0, r0 + 32);
    rmwset(v1, bs1);
  }

  // --- counting sort of the 256 column-q values (tiny) ---
  atomicAdd(&cnt2[q0], 1);
  atomicAdd(&cnt2[q1], 1);
  __syncthreads();
  if (tid == 0) {
    int run = 0;
    for (int c = 0; c < NPOS; ++c) { off2s[c] = run; off2m[c] = run; run += cnt2[c]; }
  }
  __syncthreads();
  order2[atomicAdd(&off2m[q0], 1)] = 2 * tid;
  order2[atomicAdd(&off2m[q1], 1)] = 2 * tid + 1;
  __syncthreads();

  // --- reduce: bin (p,q) = sum over this block's columns with q_c == q ---
  // (avg ~5 columns per bin; one global atomic per (block, bin))
  for (int bin = tid; bin < NBINS; bin += H_THREADS) {
    const int p  = bin / NPOS;
    const int qq = bin % NPOS;
    const int s0 = off2s[qq];
    const int n  = cnt2[qq];
    float s = 0.0f;
    for (int k = 0; k < n; ++k) {
      const int c = order2[s0 + k];
      s += (c & 1) ? accB[p][c >> 1] : accA[p][c >> 1];
    }
    atomicAdd(&g_hist[bin], s);
  }
}

// ---------------------------------------------------------------------------
// Kernel 2: out = s_arc + ALPHA * sigmoid(hist)[pos[b,i]*50 + pos[b,j]]
// Measured at ~6.1 TB/s (HBM roofline) — unchanged from the passing version.
// ---------------------------------------------------------------------------
__global__ __launch_bounds__(A_THREADS) void apply_kernel(
    const float* __restrict__ s, const int* __restrict__ pos,
    const float* __restrict__ g_hist, float* __restrict__ out) {
  __shared__ float sig[NBINS];
  __shared__ int   pos_s[SL];

  const int tid = threadIdx.x;
  const int b   = blockIdx.x / BLOCKS_PER_B;
  const int i0  = (blockIdx.x % BLOCKS_PER_B) * ROWS_PER_BLOCK;

  ((int4*)pos_s)[tid] = ((const int4*)(pos + (size_t)b * SL))[tid];
  for (int k = tid; k < NBINS; k += A_THREADS) {
    const float h = g_hist[k];
    sig[k] = 1.0f / (1.0f + __expf(-h));
  }
  __syncthreads();

  const int4 pj = ((const int4*)pos_s)[tid];
  const size_t rowoff = ((size_t)b * SL + i0) * SL;
  const float4* __restrict__ srow = (const float4*)(s + rowoff);
  float4* __restrict__ orow = (float4*)(out + rowoff);

  for (int r = 0; r < ROWS_PER_BLOCK; ++r) {
    const int base = pos_s[i0 + r] * NPOS;    // wave-uniform broadcast
    const float4 sv = srow[(size_t)r * (SL / 4) + tid];
    float4 ov;
    ov.x = sv.x + ALPHA * sig[base + pj.x];
    ov.y = sv.y + ALPHA * sig[base + pj.y];
    ov.z = sv.z + ALPHA * sig[base + pj.z];
    ov.w = sv.w + ALPHA * sig[base + pj.w];
    orow[(size_t)r * (SL / 4) + tid] = ov;
  }
}

extern "C" void kernel_launch(void* const* d_in, const int* in_sizes, int n_in,
                              void* d_out, int out_size, void* d_ws, size_t ws_size,
                              hipStream_t stream) {
  const float* a_arc = (const float*)d_in[0];
  const float* s_arc = (const float*)d_in[1];
  const int*   adds  = (const int*)d_in[2];
  const int*   pos   = (const int*)d_in[3];
  float* out    = (float*)d_out;
  float* g_hist = (float*)d_ws;   // NBINS floats = 10 KB scratch

  // d_ws is NOT re-poisoned between timed replays; zero it each call.
  hipMemsetAsync(g_hist, 0, NBINS * sizeof(float), stream);

  hist_kernel <<<H_BLOCKS, H_THREADS, 0, stream>>>(a_arc, adds, g_hist);
  apply_kernel<<<A_BLOCKS, A_THREADS, 0, stream>>>(s_arc, pos, g_hist, out);
}